// Round 8
// baseline (46.127 us; speedup 1.0000x reference)
//
#include <hip/hip_runtime.h>

#define HEADS 8
#define CH    64      // per-head dim == x channel dim
#define HW    4096
#define MTOK  256     // z tokens
#define DIMZ  256     // z feature dim
#define INNER 512     // heads*CH
#define LROWS 512     // HW/8 distinct query rows per head

typedef __attribute__((ext_vector_type(8))) __bf16 bf16x8;
typedef __attribute__((ext_vector_type(4))) float  f32x4;

// round-to-nearest-even f32 -> bf16 bits
__device__ __forceinline__ unsigned f2bf(float f) {
  unsigned u = __float_as_uint(f);
  return (u + 0x7fffu + ((u >> 16) & 1u)) >> 16;
}

__device__ __forceinline__ bf16x8 ld_bf8(const unsigned short* p) {
  uint4 v = *(const uint4*)p;
  return __builtin_bit_cast(bf16x8, v);
}

// 8 consecutive f32 -> bf16x8
__device__ __forceinline__ bf16x8 cvt8(const float* p) {
  float4 f0 = *(const float4*)p;
  float4 f1 = *(const float4*)(p + 4);
  uint4 u;
  u.x = f2bf(f0.x) | (f2bf(f0.y) << 16);
  u.y = f2bf(f0.z) | (f2bf(f0.w) << 16);
  u.z = f2bf(f1.x) | (f2bf(f1.y) << 16);
  u.w = f2bf(f1.z) | (f2bf(f1.w) << 16);
  return __builtin_bit_cast(bf16x8, u);
}

// ---------------------------------------------------------------------------
// Kernel 0 (prep_w): coalesced LDS-tiled transpose.
//   jobs 0..31  : Wk (256x512 f32) -> WkT (512x256 bf16)
//   jobs 32..63 : Wv -> WvT
//   jobs 64..71 : Wo (512x64 f32)  -> WoT (64x512 bf16)
// Each block: one 64x64 tile. Reads coalesced rows, writes coalesced
// packed-bf16 rows of the transpose; strides live in LDS (conflict-free).
// ---------------------------------------------------------------------------
__global__ __launch_bounds__(256) void prep_w(
    const float* __restrict__ Wk, const float* __restrict__ Wv,
    const float* __restrict__ Wo,
    unsigned short* __restrict__ WkT, unsigned short* __restrict__ WvT,
    unsigned short* __restrict__ WoT) {
  __shared__ float T[64][65];
  int job = blockIdx.x;
  const float* __restrict__ src;
  unsigned short* __restrict__ dst;
  int k0, n0, sld, dld;
  if (job < 32)      { src = Wk; dst = WkT; k0 = (job >> 3) * 64; n0 = (job & 7) * 64; sld = INNER; dld = DIMZ; }
  else if (job < 64) { job -= 32; src = Wv; dst = WvT; k0 = (job >> 3) * 64; n0 = (job & 7) * 64; sld = INNER; dld = DIMZ; }
  else               { job -= 64; src = Wo; dst = WoT; k0 = job * 64; n0 = 0; sld = CH; dld = INNER; }
  const int tid = threadIdx.x;
  const int rr = tid >> 6, cc = tid & 63;
#pragma unroll
  for (int it = 0; it < 16; ++it) {
    int r = it * 4 + rr;
    T[r][cc] = src[(size_t)(k0 + r) * sld + n0 + cc];
  }
  __syncthreads();
  const int nr = tid >> 5, kp = tid & 31;
#pragma unroll
  for (int it = 0; it < 8; ++it) {
    int n = it * 8 + nr;
    unsigned w = f2bf(T[kp * 2][n]) | (f2bf(T[kp * 2 + 1][n]) << 16);
    *(unsigned*)(dst + (size_t)(n0 + n) * dld + k0 + kp * 2) = w;
  }
}

// ---------------------------------------------------------------------------
// Kernel B (fused kv-gen + attention): UNCHANGED from R7 (validated).
// One block per (b, h, 128-query chunk); 512 threads = 8 waves; 128 KB LDS.
// ---------------------------------------------------------------------------
__global__ __launch_bounds__(512) void fused_attn(
    const float* __restrict__ x, const float* __restrict__ z,
    const unsigned short* __restrict__ WkT, const float* __restrict__ bk,
    const unsigned short* __restrict__ WvT, const float* __restrict__ bv,
    unsigned short* __restrict__ out2) {
  __shared__ __align__(16) char lds[131072];
  const int t = threadIdx.x;
  const int lane = t & 63, wid = t >> 6;
  const int c = lane & 15, g = lane >> 4;
  const int bid = blockIdx.x;            // qc | hh | b
  const int qc = bid & 3, hh = (bid >> 2) & 7, b = bid >> 5;

  // ---------------- Phase 1: K/V generation into LDS ----------------
  {
    const bool isK = wid < 4;
    const unsigned short* __restrict__ WT = isK ? WkT : WvT;
    const float* __restrict__ bias = isK ? bk : bv;
    const float* zs = z + ((size_t)b * MTOK + hh * 32) * DIMZ;

    f32x4 acc[4][2][2];
#pragma unroll
    for (int tt = 0; tt < 4; ++tt)
#pragma unroll
      for (int i = 0; i < 2; ++i)
#pragma unroll
        for (int j = 0; j < 2; ++j) acc[tt][i][j] = (f32x4)0.f;

#pragma unroll
    for (int s = 0; s < 8; ++s) {
      const int k0 = s * 32;
      bf16x8 a0 = cvt8(zs + (size_t)c * DIMZ + k0 + 8 * g);
      bf16x8 a1 = cvt8(zs + (size_t)(16 + c) * DIMZ + k0 + 8 * g);
#pragma unroll
      for (int tt = 0; tt < 4; ++tt) {
        const int n0 = ((wid & 3) * 4 + tt) * 32;
        bf16x8 b0 = ld_bf8(WT + (size_t)(n0 + c) * DIMZ + k0 + 8 * g);
        bf16x8 b1 = ld_bf8(WT + (size_t)(n0 + 16 + c) * DIMZ + k0 + 8 * g);
        if (isK) {   // D[n][m]: rows = feature, col = token
          acc[tt][0][0] = __builtin_amdgcn_mfma_f32_16x16x32_bf16(b0, a0, acc[tt][0][0], 0, 0, 0);
          acc[tt][0][1] = __builtin_amdgcn_mfma_f32_16x16x32_bf16(b1, a0, acc[tt][0][1], 0, 0, 0);
          acc[tt][1][0] = __builtin_amdgcn_mfma_f32_16x16x32_bf16(b0, a1, acc[tt][1][0], 0, 0, 0);
          acc[tt][1][1] = __builtin_amdgcn_mfma_f32_16x16x32_bf16(b1, a1, acc[tt][1][1], 0, 0, 0);
        } else {     // D[m][n]: rows = token, col = feature
          acc[tt][0][0] = __builtin_amdgcn_mfma_f32_16x16x32_bf16(a0, b0, acc[tt][0][0], 0, 0, 0);
          acc[tt][0][1] = __builtin_amdgcn_mfma_f32_16x16x32_bf16(a0, b1, acc[tt][0][1], 0, 0, 0);
          acc[tt][1][0] = __builtin_amdgcn_mfma_f32_16x16x32_bf16(a1, b0, acc[tt][1][0], 0, 0, 0);
          acc[tt][1][1] = __builtin_amdgcn_mfma_f32_16x16x32_bf16(a1, b1, acc[tt][1][1], 0, 0, 0);
        }
      }
    }
    if (isK) {
#pragma unroll
      for (int tt = 0; tt < 4; ++tt) {
        const int n0 = ((wid & 3) * 4 + tt) * 32;
#pragma unroll
        for (int mt = 0; mt < 2; ++mt)
#pragma unroll
          for (int nt = 0; nt < 2; ++nt) {
            const int nb4 = n0 + nt * 16 + 4 * g;    // feature quad base
            float4 b4 = *(const float4*)(bias + nb4);
            const int key = (nb4 >> 6) * 32 + mt * 16 + c;
            const int ch0 = nb4 & 63;
            uint2 w;
            w.x = f2bf(acc[tt][mt][nt][0] + b4.x) | (f2bf(acc[tt][mt][nt][1] + b4.y) << 16);
            w.y = f2bf(acc[tt][mt][nt][2] + b4.z) | (f2bf(acc[tt][mt][nt][3] + b4.w) << 16);
            *(uint2*)(lds + ((key * 128 + ch0 * 2) ^ ((key & 7) << 4))) = w;
          }
      }
    } else {
#pragma unroll
      for (int tt = 0; tt < 4; ++tt) {
        const int n0 = ((wid & 3) * 4 + tt) * 32;
#pragma unroll
        for (int mt = 0; mt < 2; ++mt)
#pragma unroll
          for (int nt = 0; nt < 2; ++nt) {
            const int n = n0 + nt * 16 + c;
            const float bn1 = bias[n];
            const int ch = n & 63;
            const int key0 = (n >> 6) * 32 + mt * 16 + 4 * g;
            uint2 w;
            w.x = f2bf(acc[tt][mt][nt][0] + bn1) | (f2bf(acc[tt][mt][nt][1] + bn1) << 16);
            w.y = f2bf(acc[tt][mt][nt][2] + bn1) | (f2bf(acc[tt][mt][nt][3] + bn1) << 16);
            *(uint2*)(lds + 32768 + ((ch * 512 + key0 * 2) ^ ((ch & 7) << 4))) = w;
          }
      }
    }
  }
  __syncthreads();

  // ---------------- Phase 2: 16-query attention per wave ----------------
  const char* Kb = lds;
  const char* Vb = lds + 32768;
  char* Pb = lds + 65536 + wid * 8192;
  const int qbase = qc * 128 + wid * 16;
  const float* xs = x + (size_t)b * (HW * CH) + (size_t)hh * (LROWS * CH);

  // Q fragment (B-operand); scale (1/8)*log2e folded in
  const float qs = 0.125f * 1.44269504089f;
  bf16x8 qfr[2];
#pragma unroll
  for (int ks = 0; ks < 2; ++ks) {
    const float* qp = xs + (size_t)(qbase + c) * CH + 32 * ks + 8 * g;
    float4 f0 = *(const float4*)qp;
    float4 f1 = *(const float4*)(qp + 4);
    uint4 u;
    u.x = f2bf(f0.x * qs) | (f2bf(f0.y * qs) << 16);
    u.y = f2bf(f0.z * qs) | (f2bf(f0.w * qs) << 16);
    u.z = f2bf(f1.x * qs) | (f2bf(f1.y * qs) << 16);
    u.w = f2bf(f1.z * qs) | (f2bf(f1.w * qs) << 16);
    qfr[ks] = __builtin_bit_cast(bf16x8, u);
  }

  // S'^T = K . Q^T : acc[kf]; key' = 16*kf + (4g+r), col q = c
  f32x4 acc[16];
#pragma unroll
  for (int kf = 0; kf < 16; ++kf) acc[kf] = (f32x4)0.f;
#pragma unroll
  for (int kf = 0; kf < 16; ++kf) {
    const int key = 16 * kf + c;
    bf16x8 a0 = __builtin_bit_cast(bf16x8,
        *(const uint4*)(Kb + ((key * 128 + 16 * g) ^ ((key & 7) << 4))));
    bf16x8 a1 = __builtin_bit_cast(bf16x8,
        *(const uint4*)(Kb + ((key * 128 + 64 + 16 * g) ^ ((key & 7) << 4))));
    acc[kf] = __builtin_amdgcn_mfma_f32_16x16x32_bf16(a0, qfr[0], acc[kf], 0, 0, 0);
    acc[kf] = __builtin_amdgcn_mfma_f32_16x16x32_bf16(a1, qfr[1], acc[kf], 0, 0, 0);
  }

  // softmax in log2 domain (normalization deferred) + P write
  float m = acc[0][0];
#pragma unroll
  for (int kf = 0; kf < 16; ++kf)
    m = fmaxf(m, fmaxf(fmaxf(acc[kf][0], acc[kf][1]),
                       fmaxf(acc[kf][2], acc[kf][3])));
  m = fmaxf(m, __shfl_xor(m, 16));
  m = fmaxf(m, __shfl_xor(m, 32));
  float sum = 0.f;
  const int rowb = c * 512;               // 256 ushort per P row
#pragma unroll
  for (int kf = 0; kf < 16; ++kf) {
    float e0 = exp2f(acc[kf][0] - m);
    float e1 = exp2f(acc[kf][1] - m);
    float e2 = exp2f(acc[kf][2] - m);
    float e3 = exp2f(acc[kf][3] - m);
    sum += (e0 + e1) + (e2 + e3);
    uint2 w;
    w.x = f2bf(e0) | (f2bf(e1) << 16);
    w.y = f2bf(e2) | (f2bf(e3) << 16);
    *(uint2*)(Pb + ((rowb + (16 * kf + 4 * g) * 2) ^ ((c & 7) << 4))) = w;
  }
  sum += __shfl_xor(sum, 16);
  sum += __shfl_xor(sum, 32);
  const float inv = 1.f / sum;
  asm volatile("" ::: "memory");  // keep P writes before P reads

  // O^T = V^T . P : o[cf], rows=channels, cols=queries
  f32x4 o[4];
#pragma unroll
  for (int cf = 0; cf < 4; ++cf) o[cf] = (f32x4)0.f;
#pragma unroll
  for (int ks = 0; ks < 8; ++ks) {
    bf16x8 p = __builtin_bit_cast(bf16x8,
        *(const uint4*)(Pb + ((c * 512 + (32 * ks + 8 * g) * 2) ^ ((c & 7) << 4))));
#pragma unroll
    for (int cf = 0; cf < 4; ++cf) {
      const int ch = 16 * cf + c;
      bf16x8 a = __builtin_bit_cast(bf16x8,
          *(const uint4*)(Vb + ((ch * 512 + (32 * ks + 8 * g) * 2) ^ ((ch & 7) << 4))));
      o[cf] = __builtin_amdgcn_mfma_f32_16x16x32_bf16(a, p, o[cf], 0, 0, 0);
    }
  }

  // normalize + store bf16
#pragma unroll
  for (int cf = 0; cf < 4; ++cf) {
    f32x4 r = o[cf] * inv;
    size_t row = (size_t)b * LROWS + qbase + c;
    uint2 w;
    w.x = f2bf(r[0]) | (f2bf(r[1]) << 16);
    w.y = f2bf(r[2]) | (f2bf(r[3]) << 16);
    *(uint2*)(out2 + row * INNER + 16 * cf * HEADS / HEADS + hh * CH + 16 * cf + 4 * g - 16 * cf) = w;
  }
}

// ---------------------------------------------------------------------------
// Kernel C (MFMA proj): O = out2 @ Wo + bo (4096x512x64), K split over 8
// waves (64 each), LDS reduce, then y[b, L*8+r] = x + O (broadcast 8x).
// 512 threads: 2 waves/SIMD; epilogue spread over all threads.
// ---------------------------------------------------------------------------
__global__ __launch_bounds__(512) void proj_mfma(
    const unsigned short* __restrict__ out2,
    const unsigned short* __restrict__ WoT, const float* __restrict__ bo,
    const float* __restrict__ x, float* __restrict__ y) {
  __shared__ __align__(16) float Sp[8][16][68];
  const int t = threadIdx.x, lane = t & 63, wid = t >> 6;
  const int c = lane & 15, g = lane >> 4;
  const int m0 = blockIdx.x * 16;            // 256 blocks over M=4096
  const int kw = wid * 64;

  f32x4 acc[4];
#pragma unroll
  for (int nt = 0; nt < 4; ++nt) acc[nt] = (f32x4)0.f;
#pragma unroll
  for (int s = 0; s < 2; ++s) {
    const int k0 = kw + s * 32;
    bf16x8 bfr = ld_bf8(out2 + (size_t)(m0 + c) * INNER + k0 + 8 * g);
#pragma unroll
    for (int nt = 0; nt < 4; ++nt) {
      bf16x8 afr = ld_bf8(WoT + (size_t)(nt * 16 + c) * INNER + k0 + 8 * g);
      acc[nt] = __builtin_amdgcn_mfma_f32_16x16x32_bf16(afr, bfr, acc[nt], 0, 0, 0);
    }
  }
#pragma unroll
  for (int nt = 0; nt < 4; ++nt)
    *(f32x4*)&Sp[wid][c][nt * 16 + 4 * g] = acc[nt];
  __syncthreads();

  // epilogue over all 512 threads: i = row-in-tile, jj -> (col quad, r-half)
  const int i = t >> 5, jj = t & 31;
  const int j0 = (jj & 15) * 4, rh = jj >> 4;
  float4 b4 = *(const float4*)(bo + j0);
  float4 o4 = b4;
#pragma unroll
  for (int w = 0; w < 8; ++w) {
    float4 s = *(const float4*)&Sp[w][i][j0];
    o4.x += s.x; o4.y += s.y; o4.z += s.z; o4.w += s.w;
  }
  const int m = m0 + i, bb = m >> 9, L = m & 511;
  const float* xr = x + (size_t)bb * (HW * CH) + (size_t)L * 8 * CH + j0;
  float*       yr = y + (size_t)bb * (HW * CH) + (size_t)L * 8 * CH + j0;
#pragma unroll
  for (int r = 0; r < 4; ++r) {
    const int rr = rh * 4 + r;
    float4 xv = *(const float4*)(xr + rr * CH);
    float4 ov = make_float4(o4.x + xv.x, o4.y + xv.y, o4.z + xv.z, o4.w + xv.w);
    *(float4*)(yr + rr * CH) = ov;
  }
}

extern "C" void kernel_launch(void* const* d_in, const int* in_sizes, int n_in,
                              void* d_out, int out_size, void* d_ws, size_t ws_size,
                              hipStream_t stream) {
  const float* x  = (const float*)d_in[0];
  const float* z  = (const float*)d_in[1];
  const float* Wk = (const float*)d_in[2];
  const float* bk = (const float*)d_in[3];
  const float* Wv = (const float*)d_in[4];
  const float* bv = (const float*)d_in[5];
  const float* Wo = (const float*)d_in[6];
  const float* bo = (const float*)d_in[7];
  float* y = (float*)d_out;

  // ws layout (ushort units): WkT 128K | WvT 128K | WoT 32K | out2 1M  (~2.6 MB)
  unsigned short* WkT  = (unsigned short*)d_ws;
  unsigned short* WvT  = WkT + (size_t)INNER * DIMZ;
  unsigned short* WoT  = WvT + (size_t)INNER * DIMZ;
  unsigned short* out2 = WoT + (size_t)CH * INNER;

  prep_w<<<72, 256, 0, stream>>>(Wk, Wv, Wo, WkT, WvT, WoT);
  fused_attn<<<256, 512, 0, stream>>>(x, z, WkT, bk, WvT, bv, out2);
  proj_mfma<<<256, 512, 0, stream>>>(out2, WoT, bo, x, y);
}